// Round 6
// baseline (180.736 us; speedup 1.0000x reference)
//
#include <hip/hip_runtime.h>
#include <math.h>

#define NFFT   2048
#define N1     1024
#define K1     1025
#define KPAD   36
#define MTOT   1097   // K1 + 2*KPAD
#define NFRAMES 1001
#define TLEN   120000
#define BATCH  8
#define FPER   120
#define PIF 3.14159265358979323846f

// ============================================================================
// One WAVE per frame, TWO independent frames per 128-thread block, ZERO
// __syncthreads. FFT data movement is BYTE-IDENTICAL to r4 (passed 3x on HW,
// absmax 0.03125): full 1024-cpx scratch, SW swizzle, same RT1/RT2/kstore.
// r6 change vs r4 is ONLY memory-lifetime packing (r5's phased-512 rewrite
// failed correctness and is abandoned):
//   - s_P (1026 f) now ALIASES s_c's first floats; legal because:
//       * pack_even drains ALL of s_P into registers before the FFT's first
//         s_c write (fence between them), and
//       * the unpack buffers all 17 Z values (zk[8], zm[8], z512) into
//         registers before the first s_P write (fence between them).
//   - s_C (1097 f) sits after s_P: per-frame LDS = 2123 floats (~8.5 KB,
//     was 12.3 KB) -> 2-wave blocks of 17 KB -> 9 blocks x 2 = 18 waves/CU
//     by LDS (VGPR=128 binds at 16; was 12). More resident waves = more
//     latency hiding for the same instruction stream.
// Spill canary: FETCH ~15.5 MB, WRITE ~32.3 MB must not grow.
// ============================================================================

typedef float2 cpx;
__device__ __forceinline__ cpx cadd(cpx a, cpx b){ return make_float2(a.x+b.x, a.y+b.y); }
__device__ __forceinline__ cpx csub(cpx a, cpx b){ return make_float2(a.x-b.x, a.y-b.y); }
__device__ __forceinline__ cpx cmul(cpx a, cpx b){ return make_float2(a.x*b.x - a.y*b.y, a.x*b.y + a.y*b.x); }

// r4's swizzle for the 1024-cpx scratch (bank-floor for all FFT patterns)
__device__ __forceinline__ int SW(int m){ return m ^ ((m >> 6) & 15); }

// W_{den}^idx = exp(-i*pi*idx/(den/2))
__device__ __forceinline__ cpx twd(float idx, float inv_half_den){
    float sn, cs;
    __sincosf(-PIF * idx * inv_half_den, &sn, &cs);
    return make_float2(cs, sn);
}

// radix-4 DIF butterfly (identical arithmetic to r1-r4)
__device__ __forceinline__ void bf4(cpx& x0, cpx& x1, cpx& x2, cpx& x3, cpx w1)
{
    cpx w1n = make_float2(w1.y, -w1.x);                       // -i*w1
    cpx w2  = make_float2(w1.x*w1.x - w1.y*w1.y, 2.0f*w1.x*w1.y);
    cpx a1 = cadd(x0, x2);
    cpx c1 = cmul(csub(x0, x2), w1);
    cpx b1 = cadd(x1, x3);
    cpx d1 = cmul(csub(x1, x3), w1n);
    x0 = cadd(a1, b1);
    x1 = cmul(csub(a1, b1), w2);
    x2 = cadd(c1, d1);
    x3 = cmul(csub(c1, d1), w2);
}
__device__ __forceinline__ void bf4_last(cpx& x0, cpx& x1, cpx& x2, cpx& x3)
{
    cpx a1 = cadd(x0, x2);
    cpx c1 = csub(x0, x2);
    cpx b1 = cadd(x1, x3);
    cpx bd = csub(x1, x3);
    cpx d1 = make_float2(bd.y, -bd.x);
    x0 = cadd(a1, b1);
    x1 = csub(a1, b1);
    x2 = cadd(c1, d1);
    x3 = csub(c1, d1);
}

// Full 1024-pt FFT from z[16] (natural order m=t+64r) to s_c in NATURAL k
// order. BYTE-IDENTICAL to r4's fft1024 (validated on HW).
__device__ __forceinline__ void fft1024(cpx z[16], cpx* s_c, int t)
{
    const int vv = t & 3;
    // stage A (M=1024): slots {j, j+4, j+8, j+12}, w = W_1024^(t+64j)
#pragma unroll
    for (int j = 0; j < 4; ++j)
        bf4(z[j], z[j+4], z[j+8], z[j+12], twd((float)(t + 64*j), 1.0f/512.0f));
    // stage B (M=256): quads, w = W_256^t
    {
        cpx wB = twd((float)t, 1.0f/128.0f);
#pragma unroll
        for (int q = 0; q < 4; ++q) bf4(z[4*q], z[4*q+1], z[4*q+2], z[4*q+3], wB);
    }
    // RT1: write m = t+64r ; read m = 64*(t>>2) + 4u + (t&3)
#pragma unroll
    for (int r = 0; r < 16; ++r) s_c[(t + 64 * r) ^ r] = z[r];
#pragma unroll
    for (int u = 0; u < 16; ++u) {
        int m = 64 * (t >> 2) + 4 * u + vv;
        z[u] = s_c[m ^ (t >> 2)];
    }
    // stage C (M=64): slots {a, a+4, a+8, a+12}, w = W_64^(4a+v)
#pragma unroll
    for (int a = 0; a < 4; ++a)
        bf4(z[a], z[a+4], z[a+8], z[a+12], twd((float)(4*a + vv), 1.0f/32.0f));
    // stage D (M=16): quads, w = W_16^v
    {
        cpx wD = twd((float)vv, 1.0f/8.0f);
#pragma unroll
        for (int h = 0; h < 4; ++h) bf4(z[4*h], z[4*h+1], z[4*h+2], z[4*h+3], wD);
    }
    // RT2: write back same layout ; read quads m = 4t + 256c + e
#pragma unroll
    for (int u = 0; u < 16; ++u) {
        int m = 64 * (t >> 2) + 4 * u + vv;
        s_c[m ^ (t >> 2)] = z[u];
    }
#pragma unroll
    for (int c = 0; c < 4; ++c)
#pragma unroll
        for (int e = 0; e < 4; ++e)
            z[4 * c + e] = s_c[SW(4 * t + 256 * c + e)];
    // stage E (M=4), then store un-bit-reversed: k = brev10(m)
#pragma unroll
    for (int c = 0; c < 4; ++c) bf4_last(z[4*c], z[4*c+1], z[4*c+2], z[4*c+3]);
    const int r6 = (int)(__brev((unsigned)t) >> 26);   // rev6(t)
#pragma unroll
    for (int c = 0; c < 4; ++c) {
        int rc = ((c & 1) << 1) | (c >> 1);
#pragma unroll
        for (int e = 0; e < 4; ++e) {
            int re = ((e & 1) << 1) | (e >> 1);
            int k = (re << 8) | (r6 << 2) | rc;
            s_c[SW(k)] = z[4 * c + e];
        }
    }
}

// pack even extension of s_P (length-2048 real-even -> 1024 cpx, m=t+64r).
// Drains ALL of s_P[0..1024] into registers (s_P dead afterwards).
__device__ __forceinline__ void pack_even(const float* s_P, cpx z[16], int t)
{
#pragma unroll
    for (int r = 0; r < 8; ++r) {
        int m = t + 64 * r;
        z[r] = make_float2(s_P[2 * m], s_P[2 * m + 1]);
    }
#pragma unroll
    for (int r = 8; r < 16; ++r) {
        int m = t + 64 * r;
        float v0, v1;
        if (m == 512) { v0 = s_P[1024]; v1 = s_P[1023]; }
        else          { v0 = s_P[2048 - 2 * m]; v1 = s_P[2047 - 2 * m]; }
        z[r] = make_float2(v0, v1);
    }
}

// conjugate pair-unpack from explicit Zk/Zm (identical math to r2-r5)
__device__ __forceinline__ void unpack2(cpx Zk, cpx Zm, cpx w, cpx& Xk, cpx& Xm)
{
    float Ex = 0.5f*(Zk.x + Zm.x), Ey = 0.5f*(Zk.y - Zm.y);
    float Ox = 0.5f*(Zk.y + Zm.y), Oy = 0.5f*(Zm.x - Zk.x);
    float tx = w.x*Ox - w.y*Oy, ty = w.x*Oy + w.y*Ox;
    Xk = make_float2(Ex + tx, Ey + ty);
    Xm = make_float2(Ex - tx, Ey - ty);
}

#define WFLOATS 2128   // per-frame: s_c floats [0,2048); s_P [0,1026); s_C [1026,2123)

__global__ __launch_bounds__(128, 1)
void cheaptrick_kernel(const float* __restrict__ x,
                       const float* __restrict__ f0in,
                       float* __restrict__ out)
{
    __shared__ float smem[2][WFLOATS];

    const int t   = threadIdx.x & 63;    // lane
    const int wid = threadIdx.x >> 6;
    const int n   = 2 * blockIdx.x + wid;
    const int b   = blockIdx.y;
    if (n >= NFRAMES) return;            // zero barriers -> early exit safe

    float* base = smem[wid];
    cpx*   s_c  = (cpx*)base;            // 1024 cpx = floats [0,2048)
    float* s_P  = base;                  // floats [0,1026)  (aliases s_c)
    float* s_C  = base + 1026;           // floats [1026,2123) (disjoint from s_P)

    float f0 = f0in[b * NFRAMES + n];
    const float F_MIN = 72000.0f / 2045.0f;
    if (f0 <= F_MIN) f0 = 500.0f;

    cpx z[16];

    // ======================= pass 0: |FFT(win*frame)|^2 =======================
    // pack1 (identical to r4): window pair parked in s_c (dead until RT1)
    {
        const float* xrow = x + (size_t)b * TLEN;
        const int base_idx = n * FPER - N1;
        float hwl = rintf(36000.0f / f0);
        float sw2 = 0.0f, swn = 0.0f, sfw = 0.0f;
#pragma unroll
        for (int r = 0; r < 16; ++r) {
            int m  = t + 64 * r;
            int i0 = base_idx + 2 * m;
            float v0, v1;
            if (i0 >= 0 && i0 + 1 <= TLEN - 1) {       // aligned pair (i0 even)
                float2 fv = *reinterpret_cast<const float2*>(xrow + i0);
                v0 = fv.x; v1 = fv.y;
            } else {
                v0 = xrow[max(0, min(TLEN - 1, i0))];
                v1 = xrow[max(0, min(TLEN - 1, i0 + 1))];
            }
            float rel0 = (float)(2 * m - N1);
            float rel1 = rel0 + 1.0f;
            float w0 = 0.0f, w1 = 0.0f;
            if (fabsf(rel0) <= hwl) w0 = 0.5f * __cosf(PIF * rel0 / 36000.0f * f0) + 0.5f;
            if (fabsf(rel1) <= hwl) w1 = 0.5f * __cosf(PIF * rel1 / 36000.0f * f0) + 0.5f;
            sw2 += w0 * w0 + w1 * w1;
            swn += w0 + w1;
            sfw += v0 * w0 + v1 * w1;
            z[r] = make_float2(v0 * w0, v1 * w1);
            s_c[SW(m)] = make_float2(w0, w1);          // park window in LDS
        }
#pragma unroll
        for (int off = 32; off > 0; off >>= 1) {
            sw2 += __shfl_down(sw2, off, 64);
            swn += __shfl_down(swn, off, 64);
            sfw += __shfl_down(sfw, off, 64);
        }
        sw2 = __shfl(sw2, 0, 64);
        swn = __shfl(swn, 0, 64);
        sfw = __shfl(sfw, 0, 64);
        float wscale = 1.0f / sqrtf(sw2);
        float dc = sfw / swn;
#pragma unroll
        for (int r = 0; r < 16; ++r) {
            cpx wnr = s_c[SW(t + 64 * r)];             // read window back
            z[r].x = wscale * (z[r].x - dc * wnr.x);
            z[r].y = wscale * (z[r].y - dc * wnr.y);
        }
    }

    fft1024(z, s_c, t);

    // buffered unpack: read ALL Z values to regs, fence, then write s_P
    // (s_P aliases s_c -> the fence keeps cpx reads before float writes)
    {
        cpx zk[8], zm[8], z512;
#pragma unroll
        for (int c = 0; c < 8; ++c) {
            int kk = t + 64 * c;
            int mm = (N1 - kk) & (N1 - 1);
            zk[c] = s_c[SW(kk)];
            zm[c] = s_c[SW(mm)];
        }
        z512 = s_c[SW(512)];                           // uniform (broadcast)
        asm volatile("" ::: "memory");
#pragma unroll
        for (int c = 0; c < 8; ++c) {
            int kk = t + 64 * c;
            cpx Xk, Xm;
            unpack2(zk[c], zm[c], twd((float)kk, 1.0f/1024.0f), Xk, Xm);
            s_P[kk]        = Xk.x * Xk.x + Xk.y * Xk.y;
            s_P[1024 - kk] = Xm.x * Xm.x + Xm.y * Xm.y;
        }
        if (t == 0) {
            cpx Xk, Xm;
            unpack2(z512, z512, make_float2(0.0f, -1.0f), Xk, Xm);
            s_P[512] = Xk.x * Xk.x + Xk.y * Xk.y;
        }
    }

    // sub-f0 replacement (kmax <= 51 < 64; reads precede the write in wave
    // program order; per-wave DS pipe is in-order)
    {
        float rate = f0 * (2048.0f / 24000.0f);
        int kmax = (int)floorf(rate);
        if (t <= kmax) {
            float m = rate - (float)t;
            int lo = (int)floorf(m);
            lo = max(0, min(K1 - 2, lo));
            float frac = m - (float)lo;
            float repl = s_P[lo] * (1.0f - frac) + s_P[lo + 1] * frac;
            s_P[t] += repl;
        }
    }

    // reflected cumsum: serial-19 + wave scan -> s_C (disjoint from s_P)
    {
        float loc[19];
        float run = 0.0f;
        const int basej = t * 19;
#pragma unroll
        for (int c = 0; c < 19; ++c) {
            int j = basej + c;
            float v = 0.0f;
            if (j < MTOT) {
                int a = abs(j - KPAD);
                if (a > N1) a = NFFT - a;
                v = s_P[a] * (24000.0f / 2048.0f);
            }
            run += v;
            loc[c] = run;
        }
        float sv = run;
#pragma unroll
        for (int off = 1; off < 64; off <<= 1) {
            float o = __shfl_up(sv, off, 64);
            if (t >= off) sv += o;
        }
        float prefix = sv - run;
#pragma unroll
        for (int c = 0; c < 19; ++c) {
            int j = basej + c;
            if (j < MTOT) s_C[j] = prefix + loc[c];
        }
    }

    // rectangular smoothing + log -> s_P
    {
        float width = f0 * (2.0f / 3.0f);
        float wbins = width * (2048.0f / 24000.0f);
#pragma unroll
        for (int c = 0; c < 17; ++c) {
            int k = t + 64 * c;
            if (k < K1) {                              // c==16 only t==0
                float pos_lo = (float)k - 0.5f * wbins + ((float)KPAD - 0.5f);
                float pos_hi = pos_lo + wbins;
                int llo = (int)floorf(pos_lo); llo = max(0, min(MTOT - 2, llo));
                float flo = pos_lo - (float)llo;
                float clo = s_C[llo] + (s_C[llo + 1] - s_C[llo]) * flo;
                int lhi = (int)floorf(pos_hi); lhi = max(0, min(MTOT - 2, lhi));
                float fhi = pos_hi - (float)lhi;
                float chi = s_C[lhi] + (s_C[lhi + 1] - s_C[lhi]) * fhi;
                s_P[k] = __logf((chi - clo) / width);
            }
        }
    }

    // ======================= pass 1: cepstrum + lifter =======================
    pack_even(s_P, z, t);                // drains s_P into regs; s_P dead
    asm volatile("" ::: "memory");       // s_P float reads before s_c cpx writes
    fft1024(z, s_c, t);

    {
        cpx zk[8], zm[8], z512;
#pragma unroll
        for (int c = 0; c < 8; ++c) {
            int kk = t + 64 * c;
            int mm = (N1 - kk) & (N1 - 1);
            zk[c] = s_c[SW(kk)];
            zm[c] = s_c[SW(mm)];
        }
        z512 = s_c[SW(512)];
        asm volatile("" ::: "memory");
#pragma unroll
        for (int c = 0; c < 8; ++c) {
            int kk = t + 64 * c;
            cpx Xk, Xm;
            unpack2(zk[c], zm[c], twd((float)kk, 1.0f/1024.0f), Xk, Xm);
            {
                float cep = Xk.x * (1.0f / 2048.0f);
                float pz = PIF * f0 * ((float)kk * (1.0f / 24000.0f));
                float s = __sinf(pz);
                float sl = (kk != 0) ? (s / pz) : 1.0f;
                s_P[kk] = cep * sl * (1.0f + 0.6f * s * s);
            }
            {
                int km = 1024 - kk;                    // in [513,1024], never 0
                float cep = Xm.x * (1.0f / 2048.0f);
                float pz = PIF * f0 * ((float)km * (1.0f / 24000.0f));
                float s = __sinf(pz);
                s_P[km] = cep * (s / pz) * (1.0f + 0.6f * s * s);
            }
        }
        if (t == 0) {
            cpx Xk, Xm;
            unpack2(z512, z512, make_float2(0.0f, -1.0f), Xk, Xm);
            float cep = Xk.x * (1.0f / 2048.0f);
            float pz = PIF * f0 * (512.0f / 24000.0f);
            float s = __sinf(pz);
            s_P[512] = cep * (s / pz) * (1.0f + 0.6f * s * s);
        }
    }

    // ======================= pass 2: final hfft + store =======================
    pack_even(s_P, z, t);
    asm volatile("" ::: "memory");
    fft1024(z, s_c, t);

    // interleaved unpack + global store (writes go to global -> no aliasing)
    {
        float* orow = out + (size_t)(b * NFRAMES + n) * K1;
#pragma unroll
        for (int c = 0; c < 8; ++c) {
            int kk = t + 64 * c;
            int mm = (N1 - kk) & (N1 - 1);
            cpx Xk, Xm;
            unpack2(s_c[SW(kk)], s_c[SW(mm)], twd((float)kk, 1.0f/1024.0f), Xk, Xm);
            orow[kk]        = Xk.x;
            orow[1024 - kk] = Xm.x;
        }
        if (t == 0) {
            cpx Z5 = s_c[SW(512)];
            cpx Xk, Xm;
            unpack2(Z5, Z5, make_float2(0.0f, -1.0f), Xk, Xm);
            orow[512] = Xk.x;
        }
    }
}

extern "C" void kernel_launch(void* const* d_in, const int* in_sizes, int n_in,
                              void* d_out, int out_size, void* d_ws, size_t ws_size,
                              hipStream_t stream) {
    (void)in_sizes; (void)n_in; (void)d_ws; (void)ws_size; (void)out_size;
    const float* x  = (const float*)d_in[0];
    const float* f0 = (const float*)d_in[1];
    float* out = (float*)d_out;
    dim3 grid((NFRAMES + 1) / 2, BATCH);
    hipLaunchKernelGGL(cheaptrick_kernel, grid, dim3(128), 0, stream, x, f0, out);
}

// Round 7
// 143.866 us; speedup vs baseline: 1.2563x; 1.2563x over previous
//
#include <hip/hip_runtime.h>
#include <math.h>

#define NFFT   2048
#define N1     1024
#define K1     1025
#define KPAD   36
#define MTOT   1097   // K1 + 2*KPAD
#define NFRAMES 1001
#define TLEN   120000
#define BATCH  8
#define FPER   120
#define PIF 3.14159265358979323846f

// ============================================================================
// One WAVE (64 threads) per frame, one frame per block, ZERO __syncthreads.
// FFT data movement BYTE-IDENTICAL to r4/r6 (validated on HW, absmax 0.03125).
// r6 lesson: VGPR 132 crossed the 128 occupancy cliff (waves/SIMD halve at
// vgpr={64,128,256}) -> 8 waves/CU. r7 gets back under 128:
//   - unpack loops FOLD Z -> output scalars while reading (pk/pm 17 floats in
//     pass 0; xk/xm 17 floats in pass 1) instead of buffering 17 raw cpx
//     (34 VGPRs). Reads still all precede aliased s_P writes (fence).
//   - 1 wave/block (no 2-frame indexing regs), grid (NFRAMES, BATCH).
//   - __launch_bounds__(64,2): empirically (r3) caps VGPR at exactly 128.
//     Demand is now ~60-70 -> no spills expected.
// LDS layout (r6, validated): s_c cpx[1024] = floats [0,2048);
//   s_P floats [0,1026) ALIASES s_c; s_C floats [1026,2123).
//   WFLOATS=2128 -> 8512 B -> ~8704 B alloc -> LDS allows 18 blocks/CU;
//   VGPR=128 binds at 16 waves/CU (r4 was 12, r6 was 8).
// Spill canary: FETCH ~15.4 MB, WRITE ~32.3 MB must not grow.
// ============================================================================

typedef float2 cpx;
__device__ __forceinline__ cpx cadd(cpx a, cpx b){ return make_float2(a.x+b.x, a.y+b.y); }
__device__ __forceinline__ cpx csub(cpx a, cpx b){ return make_float2(a.x-b.x, a.y-b.y); }
__device__ __forceinline__ cpx cmul(cpx a, cpx b){ return make_float2(a.x*b.x - a.y*b.y, a.x*b.y + a.y*b.x); }

// swizzle for the 1024-cpx scratch (bank-floor for all FFT patterns; r4)
__device__ __forceinline__ int SW(int m){ return m ^ ((m >> 6) & 15); }

// W_{den}^idx = exp(-i*pi*idx/(den/2))
__device__ __forceinline__ cpx twd(float idx, float inv_half_den){
    float sn, cs;
    __sincosf(-PIF * idx * inv_half_den, &sn, &cs);
    return make_float2(cs, sn);
}

// radix-4 DIF butterfly (identical arithmetic to r1-r6)
__device__ __forceinline__ void bf4(cpx& x0, cpx& x1, cpx& x2, cpx& x3, cpx w1)
{
    cpx w1n = make_float2(w1.y, -w1.x);                       // -i*w1
    cpx w2  = make_float2(w1.x*w1.x - w1.y*w1.y, 2.0f*w1.x*w1.y);
    cpx a1 = cadd(x0, x2);
    cpx c1 = cmul(csub(x0, x2), w1);
    cpx b1 = cadd(x1, x3);
    cpx d1 = cmul(csub(x1, x3), w1n);
    x0 = cadd(a1, b1);
    x1 = cmul(csub(a1, b1), w2);
    x2 = cadd(c1, d1);
    x3 = cmul(csub(c1, d1), w2);
}
__device__ __forceinline__ void bf4_last(cpx& x0, cpx& x1, cpx& x2, cpx& x3)
{
    cpx a1 = cadd(x0, x2);
    cpx c1 = csub(x0, x2);
    cpx b1 = cadd(x1, x3);
    cpx bd = csub(x1, x3);
    cpx d1 = make_float2(bd.y, -bd.x);
    x0 = cadd(a1, b1);
    x1 = csub(a1, b1);
    x2 = cadd(c1, d1);
    x3 = csub(c1, d1);
}

// Full 1024-pt FFT from z[16] (natural order m=t+64r) to s_c in NATURAL k
// order. BYTE-IDENTICAL to r4/r6 (validated on HW).
__device__ __forceinline__ void fft1024(cpx z[16], cpx* s_c, int t)
{
    const int vv = t & 3;
    // stage A (M=1024): slots {j, j+4, j+8, j+12}, w = W_1024^(t+64j)
#pragma unroll
    for (int j = 0; j < 4; ++j)
        bf4(z[j], z[j+4], z[j+8], z[j+12], twd((float)(t + 64*j), 1.0f/512.0f));
    // stage B (M=256): quads, w = W_256^t
    {
        cpx wB = twd((float)t, 1.0f/128.0f);
#pragma unroll
        for (int q = 0; q < 4; ++q) bf4(z[4*q], z[4*q+1], z[4*q+2], z[4*q+3], wB);
    }
    // RT1: write m = t+64r ; read m = 64*(t>>2) + 4u + (t&3)
#pragma unroll
    for (int r = 0; r < 16; ++r) s_c[(t + 64 * r) ^ r] = z[r];
#pragma unroll
    for (int u = 0; u < 16; ++u) {
        int m = 64 * (t >> 2) + 4 * u + vv;
        z[u] = s_c[m ^ (t >> 2)];
    }
    // stage C (M=64): slots {a, a+4, a+8, a+12}, w = W_64^(4a+v)
#pragma unroll
    for (int a = 0; a < 4; ++a)
        bf4(z[a], z[a+4], z[a+8], z[a+12], twd((float)(4*a + vv), 1.0f/32.0f));
    // stage D (M=16): quads, w = W_16^v
    {
        cpx wD = twd((float)vv, 1.0f/8.0f);
#pragma unroll
        for (int h = 0; h < 4; ++h) bf4(z[4*h], z[4*h+1], z[4*h+2], z[4*h+3], wD);
    }
    // RT2: write back same layout ; read quads m = 4t + 256c + e
#pragma unroll
    for (int u = 0; u < 16; ++u) {
        int m = 64 * (t >> 2) + 4 * u + vv;
        s_c[m ^ (t >> 2)] = z[u];
    }
#pragma unroll
    for (int c = 0; c < 4; ++c)
#pragma unroll
        for (int e = 0; e < 4; ++e)
            z[4 * c + e] = s_c[SW(4 * t + 256 * c + e)];
    // stage E (M=4), then store un-bit-reversed: k = brev10(m)
#pragma unroll
    for (int c = 0; c < 4; ++c) bf4_last(z[4*c], z[4*c+1], z[4*c+2], z[4*c+3]);
    const int r6 = (int)(__brev((unsigned)t) >> 26);   // rev6(t)
#pragma unroll
    for (int c = 0; c < 4; ++c) {
        int rc = ((c & 1) << 1) | (c >> 1);
#pragma unroll
        for (int e = 0; e < 4; ++e) {
            int re = ((e & 1) << 1) | (e >> 1);
            int k = (re << 8) | (r6 << 2) | rc;
            s_c[SW(k)] = z[4 * c + e];
        }
    }
}

// pack even extension of s_P (length-2048 real-even -> 1024 cpx, m=t+64r).
// Drains ALL of s_P[0..1024] into registers (s_P dead afterwards).
__device__ __forceinline__ void pack_even(const float* s_P, cpx z[16], int t)
{
#pragma unroll
    for (int r = 0; r < 8; ++r) {
        int m = t + 64 * r;
        z[r] = make_float2(s_P[2 * m], s_P[2 * m + 1]);
    }
#pragma unroll
    for (int r = 8; r < 16; ++r) {
        int m = t + 64 * r;
        float v0, v1;
        if (m == 512) { v0 = s_P[1024]; v1 = s_P[1023]; }
        else          { v0 = s_P[2048 - 2 * m]; v1 = s_P[2047 - 2 * m]; }
        z[r] = make_float2(v0, v1);
    }
}

// conjugate pair-unpack from explicit Zk/Zm (identical math to r2-r6)
__device__ __forceinline__ void unpack2(cpx Zk, cpx Zm, cpx w, cpx& Xk, cpx& Xm)
{
    float Ex = 0.5f*(Zk.x + Zm.x), Ey = 0.5f*(Zk.y - Zm.y);
    float Ox = 0.5f*(Zk.y + Zm.y), Oy = 0.5f*(Zm.x - Zk.x);
    float tx = w.x*Ox - w.y*Oy, ty = w.x*Oy + w.y*Ox;
    Xk = make_float2(Ex + tx, Ey + ty);
    Xm = make_float2(Ex - tx, Ey - ty);
}

#define WFLOATS 2128   // s_c floats [0,2048); s_P [0,1026) aliased; s_C [1026,2123)

__global__ __launch_bounds__(64, 2)
void cheaptrick_kernel(const float* __restrict__ x,
                       const float* __restrict__ f0in,
                       float* __restrict__ out)
{
    __shared__ float smem[WFLOATS];

    cpx*   s_c = (cpx*)smem;             // 1024 cpx = floats [0,2048)
    float* s_P = smem;                   // floats [0,1026)  (aliases s_c)
    float* s_C = smem + 1026;            // floats [1026,2123)

    const int t = threadIdx.x;           // 0..63 == lane (single wave)
    const int n = blockIdx.x;
    const int b = blockIdx.y;

    float f0 = f0in[b * NFRAMES + n];
    const float F_MIN = 72000.0f / 2045.0f;
    if (f0 <= F_MIN) f0 = 500.0f;

    cpx z[16];

    // ======================= pass 0: |FFT(win*frame)|^2 =======================
    // pack1 (identical to r4/r6): window pair parked in s_c (dead until RT1)
    {
        const float* xrow = x + (size_t)b * TLEN;
        const int base_idx = n * FPER - N1;
        float hwl = rintf(36000.0f / f0);
        float sw2 = 0.0f, swn = 0.0f, sfw = 0.0f;
#pragma unroll
        for (int r = 0; r < 16; ++r) {
            int m  = t + 64 * r;
            int i0 = base_idx + 2 * m;
            float v0, v1;
            if (i0 >= 0 && i0 + 1 <= TLEN - 1) {       // aligned pair (i0 even)
                float2 fv = *reinterpret_cast<const float2*>(xrow + i0);
                v0 = fv.x; v1 = fv.y;
            } else {
                v0 = xrow[max(0, min(TLEN - 1, i0))];
                v1 = xrow[max(0, min(TLEN - 1, i0 + 1))];
            }
            float rel0 = (float)(2 * m - N1);
            float rel1 = rel0 + 1.0f;
            float w0 = 0.0f, w1 = 0.0f;
            if (fabsf(rel0) <= hwl) w0 = 0.5f * __cosf(PIF * rel0 / 36000.0f * f0) + 0.5f;
            if (fabsf(rel1) <= hwl) w1 = 0.5f * __cosf(PIF * rel1 / 36000.0f * f0) + 0.5f;
            sw2 += w0 * w0 + w1 * w1;
            swn += w0 + w1;
            sfw += v0 * w0 + v1 * w1;
            z[r] = make_float2(v0 * w0, v1 * w1);
            s_c[SW(m)] = make_float2(w0, w1);          // park window in LDS
        }
#pragma unroll
        for (int off = 32; off > 0; off >>= 1) {
            sw2 += __shfl_down(sw2, off, 64);
            swn += __shfl_down(swn, off, 64);
            sfw += __shfl_down(sfw, off, 64);
        }
        sw2 = __shfl(sw2, 0, 64);
        swn = __shfl(swn, 0, 64);
        sfw = __shfl(sfw, 0, 64);
        float wscale = 1.0f / sqrtf(sw2);
        float dc = sfw / swn;
#pragma unroll
        for (int r = 0; r < 16; ++r) {
            cpx wnr = s_c[SW(t + 64 * r)];             // read window back
            z[r].x = wscale * (z[r].x - dc * wnr.x);
            z[r].y = wscale * (z[r].y - dc * wnr.y);
        }
    }

    fft1024(z, s_c, t);

    // folded unpack: read Z, convert to |X|^2 scalars immediately (17 floats,
    // not 34 cpx regs), fence, then write s_P (aliases s_c)
    {
        float pk[8], pm[8], p512;
#pragma unroll
        for (int c = 0; c < 8; ++c) {
            int kk = t + 64 * c;
            int mm = (N1 - kk) & (N1 - 1);
            cpx Xk, Xm;
            unpack2(s_c[SW(kk)], s_c[SW(mm)], twd((float)kk, 1.0f/1024.0f), Xk, Xm);
            pk[c] = Xk.x * Xk.x + Xk.y * Xk.y;
            pm[c] = Xm.x * Xm.x + Xm.y * Xm.y;
        }
        {
            cpx Z5 = s_c[SW(512)];                     // uniform (broadcast)
            cpx Xk, Xm;
            unpack2(Z5, Z5, make_float2(0.0f, -1.0f), Xk, Xm);
            p512 = Xk.x * Xk.x + Xk.y * Xk.y;
        }
        asm volatile("" ::: "memory");
#pragma unroll
        for (int c = 0; c < 8; ++c) {
            int kk = t + 64 * c;
            s_P[kk]        = pk[c];
            s_P[1024 - kk] = pm[c];
        }
        if (t == 0) s_P[512] = p512;
    }

    // sub-f0 replacement (kmax <= 51 < 64; reads precede the write in wave
    // program order; per-wave DS pipe is in-order)
    {
        float rate = f0 * (2048.0f / 24000.0f);
        int kmax = (int)floorf(rate);
        if (t <= kmax) {
            float m = rate - (float)t;
            int lo = (int)floorf(m);
            lo = max(0, min(K1 - 2, lo));
            float frac = m - (float)lo;
            float repl = s_P[lo] * (1.0f - frac) + s_P[lo + 1] * frac;
            s_P[t] += repl;
        }
    }

    // reflected cumsum: serial-19 + wave scan -> s_C (disjoint from s_P)
    {
        float loc[19];
        float run = 0.0f;
        const int basej = t * 19;
#pragma unroll
        for (int c = 0; c < 19; ++c) {
            int j = basej + c;
            float v = 0.0f;
            if (j < MTOT) {
                int a = abs(j - KPAD);
                if (a > N1) a = NFFT - a;
                v = s_P[a] * (24000.0f / 2048.0f);
            }
            run += v;
            loc[c] = run;
        }
        float sv = run;
#pragma unroll
        for (int off = 1; off < 64; off <<= 1) {
            float o = __shfl_up(sv, off, 64);
            if (t >= off) sv += o;
        }
        float prefix = sv - run;
#pragma unroll
        for (int c = 0; c < 19; ++c) {
            int j = basej + c;
            if (j < MTOT) s_C[j] = prefix + loc[c];
        }
    }

    // rectangular smoothing + log -> s_P
    {
        float width = f0 * (2.0f / 3.0f);
        float wbins = width * (2048.0f / 24000.0f);
#pragma unroll
        for (int c = 0; c < 17; ++c) {
            int k = t + 64 * c;
            if (k < K1) {                              // c==16 only t==0
                float pos_lo = (float)k - 0.5f * wbins + ((float)KPAD - 0.5f);
                float pos_hi = pos_lo + wbins;
                int llo = (int)floorf(pos_lo); llo = max(0, min(MTOT - 2, llo));
                float flo = pos_lo - (float)llo;
                float clo = s_C[llo] + (s_C[llo + 1] - s_C[llo]) * flo;
                int lhi = (int)floorf(pos_hi); lhi = max(0, min(MTOT - 2, lhi));
                float fhi = pos_hi - (float)lhi;
                float chi = s_C[lhi] + (s_C[lhi + 1] - s_C[lhi]) * fhi;
                s_P[k] = __logf((chi - clo) / width);
            }
        }
    }

    // ======================= pass 1: cepstrum + lifter =======================
    pack_even(s_P, z, t);                // drains s_P into regs; s_P dead
    asm volatile("" ::: "memory");       // s_P float reads before s_c cpx writes
    fft1024(z, s_c, t);

    // folded unpack: only Xk.x / Xm.x are needed by the lifter (17 floats)
    {
        float xk[8], xm[8], x512;
#pragma unroll
        for (int c = 0; c < 8; ++c) {
            int kk = t + 64 * c;
            int mm = (N1 - kk) & (N1 - 1);
            cpx Xk, Xm;
            unpack2(s_c[SW(kk)], s_c[SW(mm)], twd((float)kk, 1.0f/1024.0f), Xk, Xm);
            xk[c] = Xk.x;
            xm[c] = Xm.x;
        }
        {
            cpx Z5 = s_c[SW(512)];
            cpx Xk, Xm;
            unpack2(Z5, Z5, make_float2(0.0f, -1.0f), Xk, Xm);
            x512 = Xk.x;
        }
        asm volatile("" ::: "memory");
#pragma unroll
        for (int c = 0; c < 8; ++c) {
            int kk = t + 64 * c;
            {
                float cep = xk[c] * (1.0f / 2048.0f);
                float pz = PIF * f0 * ((float)kk * (1.0f / 24000.0f));
                float s = __sinf(pz);
                float sl = (kk != 0) ? (s / pz) : 1.0f;
                s_P[kk] = cep * sl * (1.0f + 0.6f * s * s);
            }
            {
                int km = 1024 - kk;                    // in [513,1024], never 0
                float cep = xm[c] * (1.0f / 2048.0f);
                float pz = PIF * f0 * ((float)km * (1.0f / 24000.0f));
                float s = __sinf(pz);
                s_P[km] = cep * (s / pz) * (1.0f + 0.6f * s * s);
            }
        }
        if (t == 0) {
            float cep = x512 * (1.0f / 2048.0f);
            float pz = PIF * f0 * (512.0f / 24000.0f);
            float s = __sinf(pz);
            s_P[512] = cep * (s / pz) * (1.0f + 0.6f * s * s);
        }
    }

    // ======================= pass 2: final hfft + store =======================
    pack_even(s_P, z, t);
    asm volatile("" ::: "memory");
    fft1024(z, s_c, t);

    // interleaved unpack + global store (writes go to global -> no aliasing)
    {
        float* orow = out + (size_t)(b * NFRAMES + n) * K1;
#pragma unroll
        for (int c = 0; c < 8; ++c) {
            int kk = t + 64 * c;
            int mm = (N1 - kk) & (N1 - 1);
            cpx Xk, Xm;
            unpack2(s_c[SW(kk)], s_c[SW(mm)], twd((float)kk, 1.0f/1024.0f), Xk, Xm);
            orow[kk]        = Xk.x;
            orow[1024 - kk] = Xm.x;
        }
        if (t == 0) {
            cpx Z5 = s_c[SW(512)];
            cpx Xk, Xm;
            unpack2(Z5, Z5, make_float2(0.0f, -1.0f), Xk, Xm);
            orow[512] = Xk.x;
        }
    }
}

extern "C" void kernel_launch(void* const* d_in, const int* in_sizes, int n_in,
                              void* d_out, int out_size, void* d_ws, size_t ws_size,
                              hipStream_t stream) {
    (void)in_sizes; (void)n_in; (void)d_ws; (void)ws_size; (void)out_size;
    const float* x  = (const float*)d_in[0];
    const float* f0 = (const float*)d_in[1];
    float* out = (float*)d_out;
    dim3 grid(NFRAMES, BATCH);
    hipLaunchKernelGGL(cheaptrick_kernel, grid, dim3(64), 0, stream, x, f0, out);
}

// Round 8
// 142.104 us; speedup vs baseline: 1.2719x; 1.0124x over previous
//
#include <hip/hip_runtime.h>
#include <math.h>

#define NFFT   2048
#define N1     1024
#define K1     1025
#define KPAD   36
#define MTOT   1097   // K1 + 2*KPAD
#define NFRAMES 1001
#define TLEN   120000
#define BATCH  8
#define FPER   120
#define PIF 3.14159265358979323846f

// ============================================================================
// One WAVE per frame, FOUR independent frames per 256-thread workgroup,
// ZERO __syncthreads (waves never interact; each owns an 8.5 KB LDS slice).
// Per-wave program BYTE-IDENTICAL to r7 (passed, absmax 0.03125, no spills).
//
// r7 finding: dur pinned at 93.5 us across r1/r4/r7 while VALUBusy varied
// 72/59/62% and LDS shrank 12.3->8.5 KB -> limiter is RESIDENCY, and it
// tracks WORKGROUPS (1-wave wgs: occ 19%; r6 2-wave wgs at 2/SIMD VGPR: same
// ~1.7 wgs/CU) -> per-CU workgroup-slot limit, not LDS/VGPR.
// r8: 4 waves/wg at constant wg slots -> ~4x resident waves.
//   LDS 4 x 8512 B = 34 KB/wg -> 4 wgs/CU (LDS) = 16 waves/CU.
//   __launch_bounds__(256,2): empirical cap law cap=256/w -> 128 VGPR
//   ((64,4)->64, (64,2)->128, (256,>=5) spills; all consistent).
// Spill canary: FETCH ~15.5 MB, WRITE ~32.3 MB must not grow.
// ============================================================================

typedef float2 cpx;
__device__ __forceinline__ cpx cadd(cpx a, cpx b){ return make_float2(a.x+b.x, a.y+b.y); }
__device__ __forceinline__ cpx csub(cpx a, cpx b){ return make_float2(a.x-b.x, a.y-b.y); }
__device__ __forceinline__ cpx cmul(cpx a, cpx b){ return make_float2(a.x*b.x - a.y*b.y, a.x*b.y + a.y*b.x); }

// swizzle for the 1024-cpx scratch (bank-floor for all FFT patterns; r4)
__device__ __forceinline__ int SW(int m){ return m ^ ((m >> 6) & 15); }

// W_{den}^idx = exp(-i*pi*idx/(den/2))
__device__ __forceinline__ cpx twd(float idx, float inv_half_den){
    float sn, cs;
    __sincosf(-PIF * idx * inv_half_den, &sn, &cs);
    return make_float2(cs, sn);
}

// radix-4 DIF butterfly (identical arithmetic to r1-r7)
__device__ __forceinline__ void bf4(cpx& x0, cpx& x1, cpx& x2, cpx& x3, cpx w1)
{
    cpx w1n = make_float2(w1.y, -w1.x);                       // -i*w1
    cpx w2  = make_float2(w1.x*w1.x - w1.y*w1.y, 2.0f*w1.x*w1.y);
    cpx a1 = cadd(x0, x2);
    cpx c1 = cmul(csub(x0, x2), w1);
    cpx b1 = cadd(x1, x3);
    cpx d1 = cmul(csub(x1, x3), w1n);
    x0 = cadd(a1, b1);
    x1 = cmul(csub(a1, b1), w2);
    x2 = cadd(c1, d1);
    x3 = cmul(csub(c1, d1), w2);
}
__device__ __forceinline__ void bf4_last(cpx& x0, cpx& x1, cpx& x2, cpx& x3)
{
    cpx a1 = cadd(x0, x2);
    cpx c1 = csub(x0, x2);
    cpx b1 = cadd(x1, x3);
    cpx bd = csub(x1, x3);
    cpx d1 = make_float2(bd.y, -bd.x);
    x0 = cadd(a1, b1);
    x1 = csub(a1, b1);
    x2 = cadd(c1, d1);
    x3 = csub(c1, d1);
}

// Full 1024-pt FFT from z[16] (natural order m=t+64r) to s_c in NATURAL k
// order. BYTE-IDENTICAL to r4/r6/r7 (validated on HW).
__device__ __forceinline__ void fft1024(cpx z[16], cpx* s_c, int t)
{
    const int vv = t & 3;
    // stage A (M=1024): slots {j, j+4, j+8, j+12}, w = W_1024^(t+64j)
#pragma unroll
    for (int j = 0; j < 4; ++j)
        bf4(z[j], z[j+4], z[j+8], z[j+12], twd((float)(t + 64*j), 1.0f/512.0f));
    // stage B (M=256): quads, w = W_256^t
    {
        cpx wB = twd((float)t, 1.0f/128.0f);
#pragma unroll
        for (int q = 0; q < 4; ++q) bf4(z[4*q], z[4*q+1], z[4*q+2], z[4*q+3], wB);
    }
    // RT1: write m = t+64r ; read m = 64*(t>>2) + 4u + (t&3)
#pragma unroll
    for (int r = 0; r < 16; ++r) s_c[(t + 64 * r) ^ r] = z[r];
#pragma unroll
    for (int u = 0; u < 16; ++u) {
        int m = 64 * (t >> 2) + 4 * u + vv;
        z[u] = s_c[m ^ (t >> 2)];
    }
    // stage C (M=64): slots {a, a+4, a+8, a+12}, w = W_64^(4a+v)
#pragma unroll
    for (int a = 0; a < 4; ++a)
        bf4(z[a], z[a+4], z[a+8], z[a+12], twd((float)(4*a + vv), 1.0f/32.0f));
    // stage D (M=16): quads, w = W_16^v
    {
        cpx wD = twd((float)vv, 1.0f/8.0f);
#pragma unroll
        for (int h = 0; h < 4; ++h) bf4(z[4*h], z[4*h+1], z[4*h+2], z[4*h+3], wD);
    }
    // RT2: write back same layout ; read quads m = 4t + 256c + e
#pragma unroll
    for (int u = 0; u < 16; ++u) {
        int m = 64 * (t >> 2) + 4 * u + vv;
        s_c[m ^ (t >> 2)] = z[u];
    }
#pragma unroll
    for (int c = 0; c < 4; ++c)
#pragma unroll
        for (int e = 0; e < 4; ++e)
            z[4 * c + e] = s_c[SW(4 * t + 256 * c + e)];
    // stage E (M=4), then store un-bit-reversed: k = brev10(m)
#pragma unroll
    for (int c = 0; c < 4; ++c) bf4_last(z[4*c], z[4*c+1], z[4*c+2], z[4*c+3]);
    const int r6 = (int)(__brev((unsigned)t) >> 26);   // rev6(t)
#pragma unroll
    for (int c = 0; c < 4; ++c) {
        int rc = ((c & 1) << 1) | (c >> 1);
#pragma unroll
        for (int e = 0; e < 4; ++e) {
            int re = ((e & 1) << 1) | (e >> 1);
            int k = (re << 8) | (r6 << 2) | rc;
            s_c[SW(k)] = z[4 * c + e];
        }
    }
}

// pack even extension of s_P (length-2048 real-even -> 1024 cpx, m=t+64r).
// Drains ALL of s_P[0..1024] into registers (s_P dead afterwards).
__device__ __forceinline__ void pack_even(const float* s_P, cpx z[16], int t)
{
#pragma unroll
    for (int r = 0; r < 8; ++r) {
        int m = t + 64 * r;
        z[r] = make_float2(s_P[2 * m], s_P[2 * m + 1]);
    }
#pragma unroll
    for (int r = 8; r < 16; ++r) {
        int m = t + 64 * r;
        float v0, v1;
        if (m == 512) { v0 = s_P[1024]; v1 = s_P[1023]; }
        else          { v0 = s_P[2048 - 2 * m]; v1 = s_P[2047 - 2 * m]; }
        z[r] = make_float2(v0, v1);
    }
}

// conjugate pair-unpack from explicit Zk/Zm (identical math to r2-r7)
__device__ __forceinline__ void unpack2(cpx Zk, cpx Zm, cpx w, cpx& Xk, cpx& Xm)
{
    float Ex = 0.5f*(Zk.x + Zm.x), Ey = 0.5f*(Zk.y - Zm.y);
    float Ox = 0.5f*(Zk.y + Zm.y), Oy = 0.5f*(Zm.x - Zk.x);
    float tx = w.x*Ox - w.y*Oy, ty = w.x*Oy + w.y*Ox;
    Xk = make_float2(Ex + tx, Ey + ty);
    Xm = make_float2(Ex - tx, Ey - ty);
}

#define WFLOATS 2128   // per wave: s_c floats [0,2048); s_P [0,1026) aliased; s_C [1026,2123)

__global__ __launch_bounds__(256, 2)
void cheaptrick_kernel(const float* __restrict__ x,
                       const float* __restrict__ f0in,
                       float* __restrict__ out)
{
    __shared__ float smem[4][WFLOATS];

    const int t   = threadIdx.x & 63;    // lane within wave
    const int wid = threadIdx.x >> 6;    // wave id = frame slot
    const int n   = 4 * blockIdx.x + wid;
    const int b   = blockIdx.y;
    if (n >= NFRAMES) return;            // zero barriers -> early exit safe

    float* base = smem[wid];
    cpx*   s_c  = (cpx*)base;            // 1024 cpx = floats [0,2048)
    float* s_P  = base;                  // floats [0,1026)  (aliases s_c)
    float* s_C  = base + 1026;           // floats [1026,2123)

    float f0 = f0in[b * NFRAMES + n];
    const float F_MIN = 72000.0f / 2045.0f;
    if (f0 <= F_MIN) f0 = 500.0f;

    cpx z[16];

    // ======================= pass 0: |FFT(win*frame)|^2 =======================
    // pack1 (identical to r7): window pair parked in s_c (dead until RT1)
    {
        const float* xrow = x + (size_t)b * TLEN;
        const int base_idx = n * FPER - N1;
        float hwl = rintf(36000.0f / f0);
        float sw2 = 0.0f, swn = 0.0f, sfw = 0.0f;
#pragma unroll
        for (int r = 0; r < 16; ++r) {
            int m  = t + 64 * r;
            int i0 = base_idx + 2 * m;
            float v0, v1;
            if (i0 >= 0 && i0 + 1 <= TLEN - 1) {       // aligned pair (i0 even)
                float2 fv = *reinterpret_cast<const float2*>(xrow + i0);
                v0 = fv.x; v1 = fv.y;
            } else {
                v0 = xrow[max(0, min(TLEN - 1, i0))];
                v1 = xrow[max(0, min(TLEN - 1, i0 + 1))];
            }
            float rel0 = (float)(2 * m - N1);
            float rel1 = rel0 + 1.0f;
            float w0 = 0.0f, w1 = 0.0f;
            if (fabsf(rel0) <= hwl) w0 = 0.5f * __cosf(PIF * rel0 / 36000.0f * f0) + 0.5f;
            if (fabsf(rel1) <= hwl) w1 = 0.5f * __cosf(PIF * rel1 / 36000.0f * f0) + 0.5f;
            sw2 += w0 * w0 + w1 * w1;
            swn += w0 + w1;
            sfw += v0 * w0 + v1 * w1;
            z[r] = make_float2(v0 * w0, v1 * w1);
            s_c[SW(m)] = make_float2(w0, w1);          // park window in LDS
        }
#pragma unroll
        for (int off = 32; off > 0; off >>= 1) {
            sw2 += __shfl_down(sw2, off, 64);
            swn += __shfl_down(swn, off, 64);
            sfw += __shfl_down(sfw, off, 64);
        }
        sw2 = __shfl(sw2, 0, 64);
        swn = __shfl(swn, 0, 64);
        sfw = __shfl(sfw, 0, 64);
        float wscale = 1.0f / sqrtf(sw2);
        float dc = sfw / swn;
#pragma unroll
        for (int r = 0; r < 16; ++r) {
            cpx wnr = s_c[SW(t + 64 * r)];             // read window back
            z[r].x = wscale * (z[r].x - dc * wnr.x);
            z[r].y = wscale * (z[r].y - dc * wnr.y);
        }
    }

    fft1024(z, s_c, t);

    // folded unpack: read Z, convert to |X|^2 scalars immediately (17 floats),
    // fence, then write s_P (aliases s_c)
    {
        float pk[8], pm[8], p512;
#pragma unroll
        for (int c = 0; c < 8; ++c) {
            int kk = t + 64 * c;
            int mm = (N1 - kk) & (N1 - 1);
            cpx Xk, Xm;
            unpack2(s_c[SW(kk)], s_c[SW(mm)], twd((float)kk, 1.0f/1024.0f), Xk, Xm);
            pk[c] = Xk.x * Xk.x + Xk.y * Xk.y;
            pm[c] = Xm.x * Xm.x + Xm.y * Xm.y;
        }
        {
            cpx Z5 = s_c[SW(512)];                     // uniform (broadcast)
            cpx Xk, Xm;
            unpack2(Z5, Z5, make_float2(0.0f, -1.0f), Xk, Xm);
            p512 = Xk.x * Xk.x + Xk.y * Xk.y;
        }
        asm volatile("" ::: "memory");
#pragma unroll
        for (int c = 0; c < 8; ++c) {
            int kk = t + 64 * c;
            s_P[kk]        = pk[c];
            s_P[1024 - kk] = pm[c];
        }
        if (t == 0) s_P[512] = p512;
    }

    // sub-f0 replacement (kmax <= 51 < 64; reads precede the write in wave
    // program order; per-wave DS pipe is in-order)
    {
        float rate = f0 * (2048.0f / 24000.0f);
        int kmax = (int)floorf(rate);
        if (t <= kmax) {
            float m = rate - (float)t;
            int lo = (int)floorf(m);
            lo = max(0, min(K1 - 2, lo));
            float frac = m - (float)lo;
            float repl = s_P[lo] * (1.0f - frac) + s_P[lo + 1] * frac;
            s_P[t] += repl;
        }
    }

    // reflected cumsum: serial-19 + wave scan -> s_C (disjoint from s_P)
    {
        float loc[19];
        float run = 0.0f;
        const int basej = t * 19;
#pragma unroll
        for (int c = 0; c < 19; ++c) {
            int j = basej + c;
            float v = 0.0f;
            if (j < MTOT) {
                int a = abs(j - KPAD);
                if (a > N1) a = NFFT - a;
                v = s_P[a] * (24000.0f / 2048.0f);
            }
            run += v;
            loc[c] = run;
        }
        float sv = run;
#pragma unroll
        for (int off = 1; off < 64; off <<= 1) {
            float o = __shfl_up(sv, off, 64);
            if (t >= off) sv += o;
        }
        float prefix = sv - run;
#pragma unroll
        for (int c = 0; c < 19; ++c) {
            int j = basej + c;
            if (j < MTOT) s_C[j] = prefix + loc[c];
        }
    }

    // rectangular smoothing + log -> s_P
    {
        float width = f0 * (2.0f / 3.0f);
        float wbins = width * (2048.0f / 24000.0f);
#pragma unroll
        for (int c = 0; c < 17; ++c) {
            int k = t + 64 * c;
            if (k < K1) {                              // c==16 only t==0
                float pos_lo = (float)k - 0.5f * wbins + ((float)KPAD - 0.5f);
                float pos_hi = pos_lo + wbins;
                int llo = (int)floorf(pos_lo); llo = max(0, min(MTOT - 2, llo));
                float flo = pos_lo - (float)llo;
                float clo = s_C[llo] + (s_C[llo + 1] - s_C[llo]) * flo;
                int lhi = (int)floorf(pos_hi); lhi = max(0, min(MTOT - 2, lhi));
                float fhi = pos_hi - (float)lhi;
                float chi = s_C[lhi] + (s_C[lhi + 1] - s_C[lhi]) * fhi;
                s_P[k] = __logf((chi - clo) / width);
            }
        }
    }

    // ======================= pass 1: cepstrum + lifter =======================
    pack_even(s_P, z, t);                // drains s_P into regs; s_P dead
    asm volatile("" ::: "memory");       // s_P float reads before s_c cpx writes
    fft1024(z, s_c, t);

    // folded unpack: only Xk.x / Xm.x are needed by the lifter (17 floats)
    {
        float xk[8], xm[8], x512;
#pragma unroll
        for (int c = 0; c < 8; ++c) {
            int kk = t + 64 * c;
            int mm = (N1 - kk) & (N1 - 1);
            cpx Xk, Xm;
            unpack2(s_c[SW(kk)], s_c[SW(mm)], twd((float)kk, 1.0f/1024.0f), Xk, Xm);
            xk[c] = Xk.x;
            xm[c] = Xm.x;
        }
        {
            cpx Z5 = s_c[SW(512)];
            cpx Xk, Xm;
            unpack2(Z5, Z5, make_float2(0.0f, -1.0f), Xk, Xm);
            x512 = Xk.x;
        }
        asm volatile("" ::: "memory");
#pragma unroll
        for (int c = 0; c < 8; ++c) {
            int kk = t + 64 * c;
            {
                float cep = xk[c] * (1.0f / 2048.0f);
                float pz = PIF * f0 * ((float)kk * (1.0f / 24000.0f));
                float s = __sinf(pz);
                float sl = (kk != 0) ? (s / pz) : 1.0f;
                s_P[kk] = cep * sl * (1.0f + 0.6f * s * s);
            }
            {
                int km = 1024 - kk;                    // in [513,1024], never 0
                float cep = xm[c] * (1.0f / 2048.0f);
                float pz = PIF * f0 * ((float)km * (1.0f / 24000.0f));
                float s = __sinf(pz);
                s_P[km] = cep * (s / pz) * (1.0f + 0.6f * s * s);
            }
        }
        if (t == 0) {
            float cep = x512 * (1.0f / 2048.0f);
            float pz = PIF * f0 * (512.0f / 24000.0f);
            float s = __sinf(pz);
            s_P[512] = cep * (s / pz) * (1.0f + 0.6f * s * s);
        }
    }

    // ======================= pass 2: final hfft + store =======================
    pack_even(s_P, z, t);
    asm volatile("" ::: "memory");
    fft1024(z, s_c, t);

    // interleaved unpack + global store (writes go to global -> no aliasing)
    {
        float* orow = out + (size_t)(b * NFRAMES + n) * K1;
#pragma unroll
        for (int c = 0; c < 8; ++c) {
            int kk = t + 64 * c;
            int mm = (N1 - kk) & (N1 - 1);
            cpx Xk, Xm;
            unpack2(s_c[SW(kk)], s_c[SW(mm)], twd((float)kk, 1.0f/1024.0f), Xk, Xm);
            orow[kk]        = Xk.x;
            orow[1024 - kk] = Xm.x;
        }
        if (t == 0) {
            cpx Z5 = s_c[SW(512)];
            cpx Xk, Xm;
            unpack2(Z5, Z5, make_float2(0.0f, -1.0f), Xk, Xm);
            orow[512] = Xk.x;
        }
    }
}

extern "C" void kernel_launch(void* const* d_in, const int* in_sizes, int n_in,
                              void* d_out, int out_size, void* d_ws, size_t ws_size,
                              hipStream_t stream) {
    (void)in_sizes; (void)n_in; (void)d_ws; (void)ws_size; (void)out_size;
    const float* x  = (const float*)d_in[0];
    const float* f0 = (const float*)d_in[1];
    float* out = (float*)d_out;
    dim3 grid((NFRAMES + 3) / 4, BATCH);
    hipLaunchKernelGGL(cheaptrick_kernel, grid, dim3(256), 0, stream, x, f0, out);
}